// Round 12
// baseline (124.647 us; speedup 1.0000x reference)
//
#include <hip/hip_runtime.h>

// (B,C,H,W) = (4,64,64,64) -> N=4096, Cr=8. Single-head attn, d_k=8, d_v=64.
#define BB 4
#define CC 64
#define NN 4096
#define LOG2E 1.44269504088896340736f

typedef __attribute__((ext_vector_type(8)))  short short8;
typedef __attribute__((ext_vector_type(4)))  short short4v;
typedef __attribute__((ext_vector_type(4)))  float f32x4;
typedef unsigned short u16;

// workspace (all bf16):
//   qws [B*N][8]  (pre-scaled by log2e)
//   kws [B*N][8]
//   vws [B][N/4][64][4]  interleaved: elem (b,m,c) at b*262144 + (m>>2)*256 + c*4 + (m&3)
#define QWS_ELEMS (BB * NN * 8)

__device__ inline u16 f2bf(float x) {
    unsigned u = __float_as_uint(x);
    u = (u + 0x7fffu + ((u >> 16) & 1u)) >> 16;   // RNE
    return (u16)u;
}
__device__ inline unsigned pack2rne(float a, float b) {
    return (unsigned)f2bf(a) | ((unsigned)f2bf(b) << 16);
}
// truncating bf16 pack of two floats in one v_perm_b32 (P only; 6x error headroom)
__device__ inline unsigned permpack(float lo, float hi) {
    return __builtin_amdgcn_perm(__float_as_uint(hi), __float_as_uint(lo), 0x07060302);
}

union SH8 {
    short8 s;
    struct Halves { short4v lo, hi; } h;
    uint4 u;
};

// ---------------------------------------------------------------------------
// Kernel 1: QKV projection (R10's best-measured form). Grid (32, 9) x 512 thr.
// blockIdx.y = block-uniform output slice (-> SGPR weight loads):
// y<8: v[8y..8y+8) into the interleaved V layout; y==8: q (log2e-scaled), k.
// ---------------------------------------------------------------------------
__global__ __launch_bounds__(512) void proj_kernel(
    const float* __restrict__ x,
    const float* __restrict__ wq, const float* __restrict__ bq,
    const float* __restrict__ wk, const float* __restrict__ bk,
    const float* __restrict__ wv, const float* __restrict__ bv,
    u16* __restrict__ ws_u)
{
    u16* qws = ws_u;
    u16* kws = ws_u + QWS_ELEMS;
    u16* vws = ws_u + 2 * QWS_ELEMS;

    const int y   = blockIdx.y;                    // 0..8, block-uniform
    const int pix = blockIdx.x * 512 + threadIdx.x;
    const int b   = pix >> 12;
    const int n   = pix & (NN - 1);
    const float* xb = x + ((size_t)b << 18) + n;

    if (y < 8) {
        const int v0 = y << 3;
        float av[8];
#pragma unroll
        for (int i = 0; i < 8; ++i) av[i] = bv[v0 + i];
#pragma unroll 8
        for (int c = 0; c < CC; ++c) {
            const float xv = xb[(size_t)c << 12];          // coalesced 256B/wave
#pragma unroll
            for (int i = 0; i < 8; ++i)
                av[i] += wv[(v0 + i) * CC + c] * xv;       // scalar (uniform) loads
        }
        u16* vdst = vws + (size_t)b * 262144 + ((n >> 2) << 8) + (n & 3);
#pragma unroll
        for (int i = 0; i < 8; ++i)
            vdst[(v0 + i) << 2] = f2bf(av[i]);
    } else {
        float aq[8], ak[8];
#pragma unroll
        for (int i = 0; i < 8; ++i) { aq[i] = bq[i]; ak[i] = bk[i]; }
#pragma unroll 8
        for (int c = 0; c < CC; ++c) {
            const float xv = xb[(size_t)c << 12];
#pragma unroll
            for (int i = 0; i < 8; ++i) {
                aq[i] += wq[i * CC + c] * xv;
                ak[i] += wk[i * CC + c] * xv;
            }
        }
        uint4 qp, kp;
        qp.x = pack2rne(aq[0] * LOG2E, aq[1] * LOG2E);
        qp.y = pack2rne(aq[2] * LOG2E, aq[3] * LOG2E);
        qp.z = pack2rne(aq[4] * LOG2E, aq[5] * LOG2E);
        qp.w = pack2rne(aq[6] * LOG2E, aq[7] * LOG2E);
        kp.x = pack2rne(ak[0], ak[1]); kp.y = pack2rne(ak[2], ak[3]);
        kp.z = pack2rne(ak[4], ak[5]); kp.w = pack2rne(ak[6], ak[7]);
        *(uint4*)&qws[(size_t)pix * 8] = qp;               // 16B/lane coalesced
        *(uint4*)&kws[(size_t)pix * 8] = kp;
    }
}

// ---------------------------------------------------------------------------
// Kernel 2: high-occupancy barrier-free attention on the 16x16 MFMA family.
// Grid 1024 x 256 thr (4 waves = 4 m-quarters) = 4096 waves = 4/SIMD
// (launch_bounds(256,4) caps regs at 128; 4 blocks/CU pack exactly).
// Block = 16 queries (qb), wave = 1024 keys in 32-m tiles.
// S: 2x mfma_f32_16x16x32 per iter (A=K[m16][k8+z], B=Q^T) -> D[m][q]:
//    lane q=l15, m=quad*4+r per tile. exp2 -> p[8] (Q pre-scaled by log2e).
// PV: A=P[q][k-slots]: slot quad*8+j holds m = quad*4+j (j<4) or
//    16+quad*4+(j-4) (j>=4) — exactly the p regs IN-LANE (identity pack).
//    V B-frags use the same slot perm via the interleaved layout: 2 b64
//    global loads per frag (L2-resident), 4 frags (c-groups) per iter.
// No LDS, no barrier in the loop; ping-pong register prefetch.
// Epilogue: l butterfly (xor 16,32) + 4-wave LDS tree on 16-f32 blobs.
// ---------------------------------------------------------------------------
__global__ __launch_bounds__(256, 4) void attn_kernel(
    const float* __restrict__ x, const float* __restrict__ gamma,
    const u16* __restrict__ ws_u, float* __restrict__ out)
{
    const u16* qws = ws_u;
    const u16* kws = ws_u + QWS_ELEMS;
    const u16* vws = ws_u + 2 * QWS_ELEMS;

    __shared__ float eb[2 * 1088];     // 8704 B tree scratch (16-f32 blobs)
    __shared__ float l_part[4 * 16];
    __shared__ float l_inv[16];

    const int tid  = threadIdx.x;
    const int w    = tid >> 6;     // 0..3 = m-quarter
    const int lane = tid & 63;
    const int l15  = lane & 15;
    const int quad = lane >> 4;    // 0..3

    const int i  = blockIdx.x;
    const int b  = i >> 8;
    const int qb = (i & 255) << 4;    // 16 queries/block
    const int bN = b << 12;

    // Q B-frag (16x16x32): lane col q=l15, k-slots quad*8+j; quad0 real.
    short8 qf = {0,0,0,0,0,0,0,0};
    if (lane < 16)
        qf = *(const short8*)(qws + (size_t)(bN + qb + l15) * 8);

    // K A-frags (16x16x32): lane row m=l15, k-slots quad*8+j; quad0 real.
    // Wave's quarter: m = w*1024 + it*32 + h*16 + l15.
    const u16* kp = kws + (size_t)(bN + (w << 10) + l15) * 8;

    // V B-frag geometry: per-iter 2048-u16 window at vp + it*2048;
    // frag for c-group g: b64 pair at og = quad*256 + g*64 + l15*4 and og+1024.
    const u16* vp = vws + (size_t)b * 262144 + (w << 16);
    const int  og0 = (quad << 8) + (l15 << 2);

    SH8 F[2][4];
    short8 kk[2][2] = {{{0,0,0,0,0,0,0,0},{0,0,0,0,0,0,0,0}},
                       {{0,0,0,0,0,0,0,0},{0,0,0,0,0,0,0,0}}};

    // tile 0 -> stage 0
#pragma unroll
    for (int g = 0; g < 4; ++g) {
        F[0][g].h.lo = *(const short4v*)(vp + og0 + (g << 6));
        F[0][g].h.hi = *(const short4v*)(vp + og0 + (g << 6) + 1024);
    }
    if (lane < 16) {
        kk[0][0] = *(const short8*)(kp);
        kk[0][1] = *(const short8*)(kp + 128);
    }

    f32x4 z4 = {0.f, 0.f, 0.f, 0.f};
    f32x4 acc[4];
#pragma unroll
    for (int g = 0; g < 4; ++g) acc[g] = z4;
    float ls = 0.f;

#pragma unroll 2
    for (int it = 0; it < 32; ++it) {
        const int cur = it & 1, nb = cur ^ 1;

        // prefetch tile it+1 (last-iter reads land in ws slack, never used)
        const u16* vq = vp + (it + 1) * 2048;
#pragma unroll
        for (int g = 0; g < 4; ++g) {
            F[nb][g].h.lo = *(const short4v*)(vq + og0 + (g << 6));
            F[nb][g].h.hi = *(const short4v*)(vq + og0 + (g << 6) + 1024);
        }
        if (lane < 16) {
            kk[nb][0] = *(const short8*)(kp + (it + 1) * 256);
            kk[nb][1] = *(const short8*)(kp + (it + 1) * 256 + 128);
        }

        // S tiles: D[m][q], lane: q=l15, m=quad*4+r (+16 for tile 1)
        f32x4 d0 = __builtin_amdgcn_mfma_f32_16x16x32_bf16(kk[cur][0], qf, z4, 0, 0, 0);
        f32x4 d1 = __builtin_amdgcn_mfma_f32_16x16x32_bf16(kk[cur][1], qf, z4, 0, 0, 0);

        float p[8];
#pragma unroll
        for (int r = 0; r < 4; ++r) { p[r] = exp2f(d0[r]); p[4 + r] = exp2f(d1[r]); }
        ls += ((p[0] + p[1]) + (p[2] + p[3])) + ((p[4] + p[5]) + (p[6] + p[7]));

        // PV A-frag: identity in-lane pack (slot quad*8+j <- p[j])
        SH8 A;
        A.u.x = permpack(p[0], p[1]); A.u.y = permpack(p[2], p[3]);
        A.u.z = permpack(p[4], p[5]); A.u.w = permpack(p[6], p[7]);

#pragma unroll
        for (int g = 0; g < 4; ++g)
            acc[g] = __builtin_amdgcn_mfma_f32_16x16x32_bf16(A.s, F[cur][g].s, acc[g], 0, 0, 0);
    }

    // l: lane holds q=l15 partial over its quad's m rows -> butterfly quads
    ls += __shfl_xor(ls, 16, 64);
    ls += __shfl_xor(ls, 32, 64);
    if (lane < 16) l_part[(w << 4) + l15] = ls;
    __syncthreads();
    if (w == 0 && lane < 16)
        l_inv[l15] = 1.0f / (l_part[l15] + l_part[16 + l15] +
                             l_part[32 + l15] + l_part[48 + l15]);

    // acc tree over 4 m-quarter waves (16-f32 blobs, opaque [lane][reg])
    if (w >= 2) {
        float* e = &eb[(w - 2) * 1088 + lane * 17];
#pragma unroll
        for (int g = 0; g < 4; ++g)
#pragma unroll
            for (int r = 0; r < 4; ++r) e[g * 4 + r] = acc[g][r];
    }
    __syncthreads();
    if (w < 2) {
        const float* e = &eb[w * 1088 + lane * 17];
#pragma unroll
        for (int g = 0; g < 4; ++g)
#pragma unroll
            for (int r = 0; r < 4; ++r) acc[g][r] += e[g * 4 + r];
    }
    __syncthreads();
    if (w == 1) {
        float* e = &eb[lane * 17];
#pragma unroll
        for (int g = 0; g < 4; ++g)
#pragma unroll
            for (int r = 0; r < 4; ++r) e[g * 4 + r] = acc[g][r];
    }
    __syncthreads();
    if (w == 0) {
        const float* e = &eb[lane * 17];
#pragma unroll
        for (int g = 0; g < 4; ++g)
#pragma unroll
            for (int r = 0; r < 4; ++r) acc[g][r] += e[g * 4 + r];

        // PV D[q][c]: lane holds q=quad*4+r rows, c=l15 (+16g) col
        const f32x4 li = *(const f32x4*)&l_inv[quad << 2];
        const float g0 = gamma[0];
#pragma unroll
        for (int g = 0; g < 4; ++g) {
            const int c = (g << 4) + l15;
            const size_t base = (((size_t)((b << 6) + c)) << 12) + qb + (quad << 2);
            const float4 xv = *(const float4*)&x[base];
            float4 o;
            o.x = xv.x + g0 * acc[g][0] * li[0];
            o.y = xv.y + g0 * acc[g][1] * li[1];
            o.z = xv.z + g0 * acc[g][2] * li[2];
            o.w = xv.w + g0 * acc[g][3] * li[3];
            *(float4*)&out[base] = o;
        }
    }
}

// ---------------------------------------------------------------------------
extern "C" void kernel_launch(void* const* d_in, const int* in_sizes, int n_in,
                              void* d_out, int out_size, void* d_ws, size_t ws_size,
                              hipStream_t stream)
{
    const float* x     = (const float*)d_in[0];
    const float* wq    = (const float*)d_in[1];
    const float* bq    = (const float*)d_in[2];
    const float* wk    = (const float*)d_in[3];
    const float* bk    = (const float*)d_in[4];
    const float* wv    = (const float*)d_in[5];
    const float* bv    = (const float*)d_in[6];
    const float* gamma = (const float*)d_in[7];
    u16*   ws  = (u16*)d_ws;
    float* out = (float*)d_out;

    hipLaunchKernelGGL(proj_kernel, dim3(BB * NN / 512, 9), dim3(512), 0, stream,
                       x, wq, bq, wk, bk, wv, bv, ws);
    hipLaunchKernelGGL(attn_kernel, dim3(BB * NN / 16), dim3(256), 0, stream,
                       x, gamma, ws, out);
}